// Round 1
// baseline (139.054 us; speedup 1.0000x reference)
//
#include <hip/hip_runtime.h>

#define NROW 32768
#define KCODE 1024

typedef short bf16x8 __attribute__((ext_vector_type(8)));
typedef float floatx4 __attribute__((ext_vector_type(4)));

// fp32 -> bf16 round-to-nearest-even (finite inputs)
static __device__ __forceinline__ unsigned short f2bf(float f) {
  unsigned int x = __float_as_uint(f);
  x += 0x7fffu + ((x >> 16) & 1u);
  return (unsigned short)(x >> 16);
}

// KA: blocks 0..511  : x [32][256][1024] f32 -> xb [N][C] bf16 (transpose) + xn2[n] = sum x^2 (fp32)
//     blocks 512..575: emb -> eb bf16 + hn[k] = 0.5*||e_k||^2 ; block 512 zeroes the loss slot
// (unchanged from the verified 135us version)
__global__ __launch_bounds__(256) void k_prep(const float* __restrict__ x,
                                              const float* __restrict__ emb,
                                              unsigned short* __restrict__ xb,
                                              float* __restrict__ xn2,
                                              unsigned short* __restrict__ eb,
                                              float* __restrict__ hn,
                                              float* __restrict__ loss) {
  __shared__ unsigned short tile[256 * 66];  // stride 66 shorts -> 33 dwords (odd): <=4-way banks
  __shared__ float xred[256];
  const int t = threadIdx.x;
  const int bid = blockIdx.x;
  if (bid < 512) {
    const int b = bid >> 4, ht = bid & 15;
    const int hw0 = ht << 6;
    const int n0 = (b << 10) + hw0;
    const int hw_l = t & 63, cs = t >> 6;
    float ss = 0.f;
    const float* xp = x + (((b << 8) + cs) << 10) + hw0 + hw_l;
    for (int i = 0; i < 64; ++i) {            // c = i*4 + cs, coalesced 256B segments along hw
      const int c = (i << 2) + cs;
      const float v = xp[(size_t)i << 12];
      ss += v * v;
      tile[c * 66 + hw_l] = f2bf(v);
    }
    xred[t] = ss;
    __syncthreads();
    if (t < 64) xn2[n0 + t] = xred[t] + xred[t + 64] + xred[t + 128] + xred[t + 192];
    // phase 2: write xb coalesced along c (4B = 2 bf16 per thread)
    const int c2 = (t & 127) * 2, hs = t >> 7;
    for (int i = 0; i < 32; ++i) {
      const int row = (i << 1) + hs;
      const unsigned int u0 = tile[c2 * 66 + row];
      const unsigned int u1 = tile[(c2 + 1) * 66 + row];
      *(unsigned int*)(xb + (((size_t)(n0 + row)) << 8) + c2) = u0 | (u1 << 16);
    }
  } else {
    if (bid == 512 && t == 0) *loss = 0.f;   // KB2 (later dispatch) is the only reader/adder
    const int w = t >> 6, lane = t & 63;
    const int kb = ((bid - 512) << 4) + (w << 2);
    for (int jj = 0; jj < 4; ++jj) {
      const int k = kb + jj;
      const float* er = emb + (k << 8);
      unsigned short* eo = eb + (k << 8);
      float ss = 0.f;
      for (int j = 0; j < 4; ++j) {
        const float v = er[j * 64 + lane];
        ss += v * v;
        eo[j * 64 + lane] = f2bf(v);
      }
      for (int off = 32; off >= 1; off >>= 1) ss += __shfl_xor(ss, off, 64);
      if (lane == 0) hn[k] = 0.5f * ss;
    }
  }
}

// KB2 (fused argmax + output + loss): 512 blocks x 256 thr, 64 rows/block, FULL 1024 codes/block.
//  - xb read exactly ONCE from HBM (old 4-quarter split re-fetched it 4x = ~50 MB extra)
//  - 4 waves split the codebook (256 codes each); each wave keeps all 64 rows' A-frags
//    resident (a[4][8], rg=4 reuse -- proven KB geometry, bit-identical MFMA accumulation)
//  - B-fragments stream straight from L2 (eb = 512 KB, per-XCD L2 resident; total B-read
//    = MFMA/4 x 1KB = 268 MB L2 ~ 7.8us agg < 8.5us MFMA floor). No es staging, no
//    in-loop barriers; 8 waves/CU (2 blocks) hide the L2 latency.
//  - winner is block-local -> gather emb rows + write [B,C,H,W] + loss here (old KC fused);
//    pval/pidx round-trip and the 3rd dispatch are gone.
__global__ __launch_bounds__(256, 2) void k_argmax_out(const unsigned short* __restrict__ xb,
                                                       const unsigned short* __restrict__ eb,
                                                       const float* __restrict__ hn,
                                                       const float* __restrict__ xn2,
                                                       const float* __restrict__ emb,
                                                       float* __restrict__ out,
                                                       float* __restrict__ loss) {
  // LDS layout (overlaid in time):
  //   phase A: best_v [0,1024) f32[4][64] | best_i [1024,2048) i32[4][64] | hn_l [2048,6144) f32[1024]
  //   phase B: sel [0,65792) f32[64][257]   (overwrites phase-A region after it is dead)
  //   idx_l [65792,66048) i32[64]           (lives across phase B)
  __shared__ __align__(16) char smem[65792 + 256];
  float* bvs  = (float*)smem;
  int*   bis  = (int*)(smem + 1024);
  float* hn_l = (float*)(smem + 2048);
  int*   idx_l = (int*)(smem + 65792);
  float* sel  = (float*)smem;

  const int t = threadIdx.x;
  const int cq = t >> 6, lane = t & 63;        // wave = code-quarter
  const int r16 = lane & 15, quad = lane >> 4;
  const int n0 = blockIdx.x << 6;              // 64 rows/block
  const int b = n0 >> 10, hw0 = n0 & 1023;

  hn_l[t] = hn[t];
  hn_l[t + 256] = hn[t + 256];
  hn_l[t + 512] = hn[t + 512];
  hn_l[t + 768] = hn[t + 768];

  // A fragments: rows n0 + rg*16 + r16 (all 4 waves same rows; L1/L2 dedups), k = quad*8 + ci*32
  bf16x8 a[4][8];
  for (int rg = 0; rg < 4; ++rg) {
    const unsigned short* xr = xb + (((size_t)(n0 + (rg << 4) + r16)) << 8) + (quad << 3);
    for (int ci = 0; ci < 8; ++ci) a[rg][ci] = *(const bf16x8*)(xr + (ci << 5));
  }

  float bv[4][4]; int bi[4][4];
  for (int rg = 0; rg < 4; ++rg)
    for (int r = 0; r < 4; ++r) { bv[rg][r] = -3.4e38f; bi[rg][r] = 0; }

  __syncthreads();                             // hn_l ready

  const unsigned short* ebq = eb + ((size_t)cq << 16);  // this wave's 256-code quarter
  for (int n16 = 0; n16 < 16; ++n16) {
    const unsigned short* ebr = ebq + (((n16 << 4) + r16) << 8) + (quad << 3);
    floatx4 acc0 = {0.f,0.f,0.f,0.f}, acc1 = {0.f,0.f,0.f,0.f};
    floatx4 acc2 = {0.f,0.f,0.f,0.f}, acc3 = {0.f,0.f,0.f,0.f};
    for (int ci = 0; ci < 8; ++ci) {
      const bf16x8 bfr = *(const bf16x8*)(ebr + (ci << 5));   // L2-direct B-frag, reused x4
      acc0 = __builtin_amdgcn_mfma_f32_16x16x32_bf16(a[0][ci], bfr, acc0, 0, 0, 0);
      acc1 = __builtin_amdgcn_mfma_f32_16x16x32_bf16(a[1][ci], bfr, acc1, 0, 0, 0);
      acc2 = __builtin_amdgcn_mfma_f32_16x16x32_bf16(a[2][ci], bfr, acc2, 0, 0, 0);
      acc3 = __builtin_amdgcn_mfma_f32_16x16x32_bf16(a[3][ci], bfr, acc3, 0, 0, 0);
    }
    const int kglob = (cq << 8) + (n16 << 4) + r16;
    const float h = hn_l[kglob];
    for (int r = 0; r < 4; ++r) {              // D: row = quad*4 + r, col(code) = r16
      float v;
      v = acc0[r] - h; if (v > bv[0][r]) { bv[0][r] = v; bi[0][r] = kglob; }
      v = acc1[r] - h; if (v > bv[1][r]) { bv[1][r] = v; bi[1][r] = kglob; }
      v = acc2[r] - h; if (v > bv[2][r]) { bv[2][r] = v; bi[2][r] = kglob; }
      v = acc3[r] - h; if (v > bv[3][r]) { bv[3][r] = v; bi[3][r] = kglob; }
    }
  }
  // reduce across the 16 code-columns (within each 16-lane group); ties -> lowest index
  for (int off = 8; off >= 1; off >>= 1)
    for (int rg = 0; rg < 4; ++rg)
      for (int r = 0; r < 4; ++r) {
        const float ov = __shfl_xor(bv[rg][r], off, 64);
        const int   oi = __shfl_xor(bi[rg][r], off, 64);
        if (ov > bv[rg][r] || (ov == bv[rg][r] && oi < bi[rg][r])) { bv[rg][r] = ov; bi[rg][r] = oi; }
      }
  if (r16 == 0) {
    for (int rg = 0; rg < 4; ++rg)
      for (int r = 0; r < 4; ++r) {
        const int row = (rg << 4) + (quad << 2) + r;
        bvs[(cq << 6) + row] = bv[rg][r];
        bis[(cq << 6) + row] = bi[rg][r];
      }
  }
  __syncthreads();

  // merge the 4 code-quarters (ascending q: strict > keeps lowest code on ties) + loss
  if (t < 64) {
    float vm = bvs[t]; int im = bis[t];
    for (int q = 1; q < 4; ++q) {
      const float v = bvs[(q << 6) + t];
      if (v > vm) { vm = v; im = bis[(q << 6) + t]; }
    }
    idx_l[t] = im;
    float lv = xn2[n0 + t] - 2.f * vm;         // = ||x_n - e_{im}||^2
    for (int off = 32; off >= 1; off >>= 1) lv += __shfl_xor(lv, off, 64);
    if (t == 0) atomicAdd(loss, lv * (1.25f / 8388608.0f));
  }
  __syncthreads();                             // phase-A LDS dead; sel may overwrite

  // gather winning code rows into LDS (coalesced 256B loads from L2-resident emb)
  {
    const int w = t >> 6;
    for (int i = 0; i < 16; ++i) {
      const int row = (w << 4) + i;
      const float* er = emb + ((size_t)idx_l[row] << 8);
      for (int j = 0; j < 4; ++j)
        sel[row * 257 + (j << 6) + lane] = er[(j << 6) + lane];
    }
  }
  __syncthreads();
  // write out: float4 along hw (16B/lane), 256B segments per c
  const int hwq = t & 15, cg = t >> 4;
  const size_t base = ((size_t)b << 18);       // b*256*1024
  for (int it = 0; it < 16; ++it) {
    const int c = (it << 4) + cg;
    float4 v;
    v.x = sel[(hwq * 4 + 0) * 257 + c];
    v.y = sel[(hwq * 4 + 1) * 257 + c];
    v.z = sel[(hwq * 4 + 2) * 257 + c];
    v.w = sel[(hwq * 4 + 3) * 257 + c];
    *(float4*)(out + base + ((size_t)c << 10) + hw0 + (hwq << 2)) = v;
  }
}

extern "C" void kernel_launch(void* const* d_in, const int* in_sizes, int n_in,
                              void* d_out, int out_size, void* d_ws, size_t ws_size,
                              hipStream_t stream) {
  const float* x   = (const float*)d_in[0];
  const float* emb = (const float*)d_in[1];
  float* out  = (float*)d_out;
  float* loss = out + 8388608;

  char* ws = (char*)d_ws;
  unsigned short* xb = (unsigned short*)(ws);              // 16,777,216 B
  unsigned short* eb = (unsigned short*)(ws + 16777216);   //    524,288 B
  float* hn   = (float*)(ws + 17301504);                   //      4,096 B
  float* xn2  = (float*)(ws + 17305600);                   //    131,072 B

  k_prep<<<576, 256, 0, stream>>>(x, emb, xb, xn2, eb, hn, loss);
  k_argmax_out<<<512, 256, 0, stream>>>(xb, eb, hn, xn2, emb, out, loss);
}

// Round 2
// 128.003 us; speedup vs baseline: 1.0863x; 1.0863x over previous
//
#include <hip/hip_runtime.h>

#define NROW 32768
#define KCODE 1024

typedef short bf16x8 __attribute__((ext_vector_type(8)));
typedef float floatx4 __attribute__((ext_vector_type(4)));

// fp32 -> bf16 round-to-nearest-even (finite inputs)
static __device__ __forceinline__ unsigned short f2bf(float f) {
  unsigned int x = __float_as_uint(f);
  x += 0x7fffu + ((x >> 16) & 1u);
  return (unsigned short)(x >> 16);
}

// KA: blocks 0..511  : x [32][256][1024] f32 -> xb [N][C] bf16 (transpose) + xn2[n] = sum x^2 (fp32)
//     blocks 512..575: emb -> eb bf16 + hn[k] = 0.5*||e_k||^2 ; block 512 zeroes the loss slot
// (unchanged from the verified 135us version)
__global__ __launch_bounds__(256) void k_prep(const float* __restrict__ x,
                                              const float* __restrict__ emb,
                                              unsigned short* __restrict__ xb,
                                              float* __restrict__ xn2,
                                              unsigned short* __restrict__ eb,
                                              float* __restrict__ hn,
                                              float* __restrict__ loss) {
  __shared__ unsigned short tile[256 * 66];  // stride 66 shorts -> 33 dwords (odd): <=4-way banks
  __shared__ float xred[256];
  const int t = threadIdx.x;
  const int bid = blockIdx.x;
  if (bid < 512) {
    const int b = bid >> 4, ht = bid & 15;
    const int hw0 = ht << 6;
    const int n0 = (b << 10) + hw0;
    const int hw_l = t & 63, cs = t >> 6;
    float ss = 0.f;
    const float* xp = x + (((b << 8) + cs) << 10) + hw0 + hw_l;
    for (int i = 0; i < 64; ++i) {            // c = i*4 + cs, coalesced 256B segments along hw
      const int c = (i << 2) + cs;
      const float v = xp[(size_t)i << 12];
      ss += v * v;
      tile[c * 66 + hw_l] = f2bf(v);
    }
    xred[t] = ss;
    __syncthreads();
    if (t < 64) xn2[n0 + t] = xred[t] + xred[t + 64] + xred[t + 128] + xred[t + 192];
    // phase 2: write xb coalesced along c (4B = 2 bf16 per thread)
    const int c2 = (t & 127) * 2, hs = t >> 7;
    for (int i = 0; i < 32; ++i) {
      const int row = (i << 1) + hs;
      const unsigned int u0 = tile[c2 * 66 + row];
      const unsigned int u1 = tile[(c2 + 1) * 66 + row];
      *(unsigned int*)(xb + (((size_t)(n0 + row)) << 8) + c2) = u0 | (u1 << 16);
    }
  } else {
    if (bid == 512 && t == 0) *loss = 0.f;   // KB3 (later dispatch) is the only reader/adder
    const int w = t >> 6, lane = t & 63;
    const int kb = ((bid - 512) << 4) + (w << 2);
    for (int jj = 0; jj < 4; ++jj) {
      const int k = kb + jj;
      const float* er = emb + (k << 8);
      unsigned short* eo = eb + (k << 8);
      float ss = 0.f;
      for (int j = 0; j < 4; ++j) {
        const float v = er[j * 64 + lane];
        ss += v * v;
        eo[j * 64 + lane] = f2bf(v);
      }
      for (int off = 32; off >= 1; off >>= 1) ss += __shfl_xor(ss, off, 64);
      if (lane == 0) hn[k] = 0.5f * ss;
    }
  }
}

// KB3 (fused, LDS-staged): 256 blocks x 512 thr x 128 rows, FULL 1024 codes/block.
// 8 waves = 4 code-quarters x 2 row-halves; each wave: a[4][8] resident (proven geometry,
// A-reuse=4 per ds_read_b128, bit-identical MFMA accumulation to baseline).
// E staged in 64-code tiles (16/quarter, es row = cq*16 + j), DOUBLE-BUFFERED, one barrier
// per tile, VGPR prefetch one tile ahead.  Per-CU: LDS ~7.7us < MFMA floor 8.3us -> MFMA-bound.
// Winner block-local -> gather + out-write + loss fused (sel overlays dead es).
// R1 post-mortem: L2-direct B-frags (no staging) = MfmaUtil 11% / 56us. Staging is mandatory.
__global__ __launch_bounds__(512, 2) void k_fullk(const unsigned short* __restrict__ xb,
                                                  const unsigned short* __restrict__ eb,
                                                  const float* __restrict__ hn,
                                                  const float* __restrict__ xn2,
                                                  const float* __restrict__ emb,
                                                  float* __restrict__ out,
                                                  float* __restrict__ loss) {
  // LDS map (bytes):
  //   [0, 67584)        es[2][64*264] shorts (double buffer; 33792 B each)
  //                     -- overlaid later by sel[64][257] f32 (65792 B)
  //   [67584, 71680)    hn_l[1024] f32
  //   [71680, 73728)    bvs[4][128] f32
  //   [73728, 75776)    bis[4][128] i32
  //   [75776, 76288)    idx_l[128] i32
  __shared__ __align__(16) char smem[76288];
  unsigned short* es0 = (unsigned short*)smem;
  unsigned short* es1 = (unsigned short*)(smem + 33792);
  float* sel  = (float*)smem;
  float* hn_l = (float*)(smem + 67584);
  float* bvs  = (float*)(smem + 71680);
  int*   bis  = (int*)(smem + 73728);
  int*   idx_l = (int*)(smem + 75776);

  const int t = threadIdx.x;
  const int w = t >> 6, lane = t & 63;
  const int cq = w & 3, rh = w >> 2;           // code-quarter, row-half
  const int r16 = lane & 15, quad = lane >> 4;
  const int n0 = blockIdx.x << 7;              // 128 rows/block

  hn_l[t] = hn[t];
  hn_l[t + 512] = hn[t + 512];

  // A fragments: rows n0 + rh*64 + rg*16 + r16, k-chunk quad*8 + ci*32
  bf16x8 a[4][8];
  for (int rg = 0; rg < 4; ++rg) {
    const unsigned short* xr = xb + (((size_t)(n0 + (rh << 6) + (rg << 4) + r16)) << 8) + (quad << 3);
    for (int ci = 0; ci < 8; ++ci) a[rg][ci] = *(const bf16x8*)(xr + (ci << 5));
  }

  // staging role: row-group g (0..15) stages es rows g+16i (i<4), cols c32*8shorts..+8
  // es row r <-> code (r>>4)*256 + kt*16 + (r&15)  => for r=g+16i: k = i*256 + kt*16 + g
  const int g = t >> 5, c32 = (t & 31) << 3;
  const int loff = g * 264 + c32;
  bf16x8 pf[4];

  // prologue: tile0 -> es0; issue tile1 prefetch
  {
    const unsigned short* src = eb + ((size_t)(g) << 8) + c32;           // kt=0
    for (int i = 0; i < 4; ++i) pf[i] = *(const bf16x8*)(src + ((size_t)i << 16));
    for (int i = 0; i < 4; ++i) *(bf16x8*)(&es0[loff + i * (16 * 264)]) = pf[i];
    const unsigned short* src1 = eb + ((size_t)(16 + g) << 8) + c32;     // kt=1
    for (int i = 0; i < 4; ++i) pf[i] = *(const bf16x8*)(src1 + ((size_t)i << 16));
  }

  float bv[4][4]; int bi[4][4];
  for (int rg = 0; rg < 4; ++rg)
    for (int r = 0; r < 4; ++r) { bv[rg][r] = -3.4e38f; bi[rg][r] = 0; }

  __syncthreads();                             // es0 + hn_l ready

  int cur = 0;
  for (int kt = 0; kt < 16; ++kt) {
    unsigned short* esc = cur ? es1 : es0;
    unsigned short* esn = cur ? es0 : es1;
    if (kt < 15)                               // write tile kt+1 (pf) into the other buffer
      for (int i = 0; i < 4; ++i) *(bf16x8*)(&esn[loff + i * (16 * 264)]) = pf[i];
    if (kt < 14) {                             // issue prefetch of tile kt+2
      const unsigned short* src = eb + ((size_t)(((kt + 2) << 4) + g) << 8) + c32;
      for (int i = 0; i < 4; ++i) pf[i] = *(const bf16x8*)(src + ((size_t)i << 16));
    }
    // compute: this wave's 16 codes (es rows cq*16 + r16) vs its 64 rows
    const unsigned short* esr = &esc[((cq << 4) + r16) * 264 + (quad << 3)];
    floatx4 acc0 = {0.f,0.f,0.f,0.f}, acc1 = {0.f,0.f,0.f,0.f};
    floatx4 acc2 = {0.f,0.f,0.f,0.f}, acc3 = {0.f,0.f,0.f,0.f};
    for (int ci = 0; ci < 8; ++ci) {
      const bf16x8 bfr = *(const bf16x8*)(esr + (ci << 5));  // 1 read feeds 4 MFMAs
      acc0 = __builtin_amdgcn_mfma_f32_16x16x32_bf16(a[0][ci], bfr, acc0, 0, 0, 0);
      acc1 = __builtin_amdgcn_mfma_f32_16x16x32_bf16(a[1][ci], bfr, acc1, 0, 0, 0);
      acc2 = __builtin_amdgcn_mfma_f32_16x16x32_bf16(a[2][ci], bfr, acc2, 0, 0, 0);
      acc3 = __builtin_amdgcn_mfma_f32_16x16x32_bf16(a[3][ci], bfr, acc3, 0, 0, 0);
    }
    const int kglob = (cq << 8) + (kt << 4) + r16;
    const float h = hn_l[kglob];
    for (int r = 0; r < 4; ++r) {              // D: row = quad*4 + r, col(code) = r16
      float v;
      v = acc0[r] - h; if (v > bv[0][r]) { bv[0][r] = v; bi[0][r] = kglob; }
      v = acc1[r] - h; if (v > bv[1][r]) { bv[1][r] = v; bi[1][r] = kglob; }
      v = acc2[r] - h; if (v > bv[2][r]) { bv[2][r] = v; bi[2][r] = kglob; }
      v = acc3[r] - h; if (v > bv[3][r]) { bv[3][r] = v; bi[3][r] = kglob; }
    }
    __syncthreads();                           // my reads + my writes done before buffers flip
    cur ^= 1;
  }

  // reduce across the 16 code-columns (within each 16-lane group); ties -> lowest index
  for (int off = 8; off >= 1; off >>= 1)
    for (int rg = 0; rg < 4; ++rg)
      for (int r = 0; r < 4; ++r) {
        const float ov = __shfl_xor(bv[rg][r], off, 64);
        const int   oi = __shfl_xor(bi[rg][r], off, 64);
        if (ov > bv[rg][r] || (ov == bv[rg][r] && oi < bi[rg][r])) { bv[rg][r] = ov; bi[rg][r] = oi; }
      }
  if (r16 == 0) {
    for (int rg = 0; rg < 4; ++rg)
      for (int r = 0; r < 4; ++r) {
        const int row = (rh << 6) + (rg << 4) + (quad << 2) + r;
        bvs[(cq << 7) + row] = bv[rg][r];
        bis[(cq << 7) + row] = bi[rg][r];
      }
  }
  __syncthreads();

  // merge 4 quarters per row (ascending q: strict > keeps lowest code on ties) + loss
  if (t < 128) {
    float vm = bvs[t]; int im = bis[t];
    for (int q = 1; q < 4; ++q) {
      const float v = bvs[(q << 7) + t];
      if (v > vm) { vm = v; im = bis[(q << 7) + t]; }
    }
    idx_l[t] = im;
    float lv = xn2[n0 + t] - 2.f * vm;         // = ||x_n - e_{im}||^2
    for (int off = 32; off >= 1; off >>= 1) lv += __shfl_xor(lv, off, 64);
    if (lane == 0) atomicAdd(loss, lv * (1.25f / 8388608.0f));
  }
  __syncthreads();                             // phase-A LDS (es) dead; sel may overwrite

  // output: two passes of 64 rows (sel = 64x257 f32 overlays es)
  for (int p = 0; p < 2; ++p) {
    const int rbase = p << 6;
    // gather winning code rows into LDS (coalesced 256B loads from L2-resident emb)
    for (int i = 0; i < 8; ++i) {
      const int row = (w << 3) + i;
      const float* er = emb + ((size_t)idx_l[rbase + row] << 8);
      for (int j = 0; j < 4; ++j)
        sel[row * 257 + (j << 6) + lane] = er[(j << 6) + lane];
    }
    __syncthreads();
    const int n0p = n0 + rbase;
    const int b = n0p >> 10, hw0 = n0p & 1023;
    const int hwq = t & 15, cg = t >> 4;       // cg 0..31
    const size_t base = ((size_t)b << 18);     // b*256*1024
    for (int it = 0; it < 8; ++it) {
      const int c = (it << 5) + cg;
      float4 v;
      v.x = sel[(hwq * 4 + 0) * 257 + c];
      v.y = sel[(hwq * 4 + 1) * 257 + c];
      v.z = sel[(hwq * 4 + 2) * 257 + c];
      v.w = sel[(hwq * 4 + 3) * 257 + c];
      *(float4*)(out + base + ((size_t)c << 10) + hw0 + (hwq << 2)) = v;
    }
    __syncthreads();                           // sel consumed before next pass overwrites
  }
}

extern "C" void kernel_launch(void* const* d_in, const int* in_sizes, int n_in,
                              void* d_out, int out_size, void* d_ws, size_t ws_size,
                              hipStream_t stream) {
  const float* x   = (const float*)d_in[0];
  const float* emb = (const float*)d_in[1];
  float* out  = (float*)d_out;
  float* loss = out + 8388608;

  char* ws = (char*)d_ws;
  unsigned short* xb = (unsigned short*)(ws);              // 16,777,216 B
  unsigned short* eb = (unsigned short*)(ws + 16777216);   //    524,288 B
  float* hn   = (float*)(ws + 17301504);                   //      4,096 B
  float* xn2  = (float*)(ws + 17305600);                   //    131,072 B

  k_prep<<<576, 256, 0, stream>>>(x, emb, xb, xn2, eb, hn, loss);
  k_fullk<<<256, 512, 0, stream>>>(xb, eb, hn, xn2, emb, out, loss);
}

// Round 4
// 125.328 us; speedup vs baseline: 1.1095x; 1.0213x over previous
//
#include <hip/hip_runtime.h>

#define NROW 32768
#define KCODE 1024

typedef short bf16x8 __attribute__((ext_vector_type(8)));
typedef float floatx4 __attribute__((ext_vector_type(4)));

// fp32 -> bf16 round-to-nearest-even (finite inputs)
static __device__ __forceinline__ unsigned short f2bf(float f) {
  unsigned int x = __float_as_uint(f);
  x += 0x7fffu + ((x >> 16) & 1u);
  return (unsigned short)(x >> 16);
}

// KA: blocks 0..511  : x [32][256][1024] f32 -> xb [N][C] bf16 (transpose) + xn2[n] = sum x^2 (fp32)
//     blocks 512..575: emb -> eb bf16 + hn[k] = 0.5*||e_k||^2 ; block 512 zeroes the loss slot
// (unchanged from the verified 135us version)
__global__ __launch_bounds__(256) void k_prep(const float* __restrict__ x,
                                              const float* __restrict__ emb,
                                              unsigned short* __restrict__ xb,
                                              float* __restrict__ xn2,
                                              unsigned short* __restrict__ eb,
                                              float* __restrict__ hn,
                                              float* __restrict__ loss) {
  __shared__ unsigned short tile[256 * 66];  // stride 66 shorts -> 33 dwords (odd): <=4-way banks
  __shared__ float xred[256];
  const int t = threadIdx.x;
  const int bid = blockIdx.x;
  if (bid < 512) {
    const int b = bid >> 4, ht = bid & 15;
    const int hw0 = ht << 6;
    const int n0 = (b << 10) + hw0;
    const int hw_l = t & 63, cs = t >> 6;
    float ss = 0.f;
    const float* xp = x + (((b << 8) + cs) << 10) + hw0 + hw_l;
    for (int i = 0; i < 64; ++i) {            // c = i*4 + cs, coalesced 256B segments along hw
      const int c = (i << 2) + cs;
      const float v = xp[(size_t)i << 12];
      ss += v * v;
      tile[c * 66 + hw_l] = f2bf(v);
    }
    xred[t] = ss;
    __syncthreads();
    if (t < 64) xn2[n0 + t] = xred[t] + xred[t + 64] + xred[t + 128] + xred[t + 192];
    // phase 2: write xb coalesced along c (4B = 2 bf16 per thread)
    const int c2 = (t & 127) * 2, hs = t >> 7;
    for (int i = 0; i < 32; ++i) {
      const int row = (i << 1) + hs;
      const unsigned int u0 = tile[c2 * 66 + row];
      const unsigned int u1 = tile[(c2 + 1) * 66 + row];
      *(unsigned int*)(xb + (((size_t)(n0 + row)) << 8) + c2) = u0 | (u1 << 16);
    }
  } else {
    if (bid == 512 && t == 0) *loss = 0.f;   // KB4 (later dispatch) is the only reader/adder
    const int w = t >> 6, lane = t & 63;
    const int kb = ((bid - 512) << 4) + (w << 2);
    for (int jj = 0; jj < 4; ++jj) {
      const int k = kb + jj;
      const float* er = emb + (k << 8);
      unsigned short* eo = eb + (k << 8);
      float ss = 0.f;
      for (int j = 0; j < 4; ++j) {
        const float v = er[j * 64 + lane];
        ss += v * v;
        eo[j * 64 + lane] = f2bf(v);
      }
      for (int off = 32; off >= 1; off >>= 1) ss += __shfl_xor(ss, off, 64);
      if (lane == 0) hn[k] = 0.5f * ss;
    }
  }
}

// KB4 (fused, LDS-staged, 2 blocks/CU): 512 blocks x 256 thr x 64 rows, FULL 1024 codes/block.
// 4 waves = 4 code-quarters; every wave holds the block's 64 rows as a[4][8] (proven geometry,
// A-reuse=4 per ds_read_b128, bit-identical MFMA accumulation; L1 dedups the 4x A-issue --
// R1 measured FETCH=14.4MB). E in 64-code tiles, DOUBLE-BUFFERED, 1 barrier/tile, VGPR
// prefetch 2 tiles ahead. LDS 74KB -> 2 blocks/CU (148<=160KB).
// R2 post-mortem: same loop at grid 256 (1 block/CU) = 44.7us, MfmaUtil 14%, ~28us of
// barrier-drain stall -- NO co-resident block to cover the per-tile vmcnt(0)+lgkmcnt(0)
// drain (m114 mechanism). 2 blocks/CU restores cross-block overlap of the drains.
// (R3 was an infra failure -- container died twice; identical resubmission.)
__global__ __launch_bounds__(256, 2) void k_fullk(const unsigned short* __restrict__ xb,
                                                  const unsigned short* __restrict__ eb,
                                                  const float* __restrict__ hn,
                                                  const float* __restrict__ xn2,
                                                  const float* __restrict__ emb,
                                                  float* __restrict__ out,
                                                  float* __restrict__ loss) {
  // LDS map (bytes):
  //   [0, 67584)        es[2][64*264] shorts (double buffer; 33792 B each)
  //                     -- overlaid later by sel[64][257] f32 (65792 B)
  //   [67584, 71680)    hn_l[1024] f32
  //   [71680, 72704)    bvs[4][64] f32
  //   [72704, 73728)    bis[4][64] i32
  //   [73728, 73984)    idx_l[64] i32
  __shared__ __align__(16) char smem[73984];
  unsigned short* es0 = (unsigned short*)smem;
  unsigned short* es1 = (unsigned short*)(smem + 33792);
  float* sel  = (float*)smem;
  float* hn_l = (float*)(smem + 67584);
  float* bvs  = (float*)(smem + 71680);
  int*   bis  = (int*)(smem + 72704);
  int*   idx_l = (int*)(smem + 73728);

  const int t = threadIdx.x;
  const int cq = t >> 6, lane = t & 63;        // wave = code-quarter
  const int r16 = lane & 15, quad = lane >> 4;
  const int n0 = blockIdx.x << 6;              // 64 rows/block
  const int b = n0 >> 10, hw0 = n0 & 1023;

  hn_l[t] = hn[t];
  hn_l[t + 256] = hn[t + 256];
  hn_l[t + 512] = hn[t + 512];
  hn_l[t + 768] = hn[t + 768];

  // A fragments: rows n0 + rg*16 + r16 (all 4 waves same rows; L1 dedups), k = quad*8 + ci*32
  bf16x8 a[4][8];
  for (int rg = 0; rg < 4; ++rg) {
    const unsigned short* xr = xb + (((size_t)(n0 + (rg << 4) + r16)) << 8) + (quad << 3);
    for (int ci = 0; ci < 8; ++ci) a[rg][ci] = *(const bf16x8*)(xr + (ci << 5));
  }

  // staging: thread (g = t>>5, c32 = (t&31)*8 shorts) stages es rows g*8+i (i<8).
  // es row r <-> code (r>>4)*256 + kt*16 + (r&15)
  const int g = t >> 5, c32 = (t & 31) << 3;
  bf16x8 pf[8];

  // prologue: tile0 -> es0; issue tile1 prefetch
  {
    for (int i = 0; i < 8; ++i) {
      const int r = (g << 3) + i;
      const int code = ((r >> 4) << 8) + (r & 15);                  // kt=0
      pf[i] = *(const bf16x8*)(eb + ((size_t)code << 8) + c32);
    }
    for (int i = 0; i < 8; ++i) *(bf16x8*)(&es0[((g << 3) + i) * 264 + c32]) = pf[i];
    for (int i = 0; i < 8; ++i) {
      const int r = (g << 3) + i;
      const int code = ((r >> 4) << 8) + 16 + (r & 15);             // kt=1
      pf[i] = *(const bf16x8*)(eb + ((size_t)code << 8) + c32);
    }
  }

  float bv[4][4]; int bi[4][4];
  for (int rg = 0; rg < 4; ++rg)
    for (int r = 0; r < 4; ++r) { bv[rg][r] = -3.4e38f; bi[rg][r] = 0; }

  __syncthreads();                             // es0 + hn_l ready

  int cur = 0;
  for (int kt = 0; kt < 16; ++kt) {
    unsigned short* esc = cur ? es1 : es0;
    unsigned short* esn = cur ? es0 : es1;
    if (kt < 15)                               // write tile kt+1 (pf) into the other buffer
      for (int i = 0; i < 8; ++i) *(bf16x8*)(&esn[((g << 3) + i) * 264 + c32]) = pf[i];
    if (kt < 14) {                             // issue prefetch of tile kt+2
      for (int i = 0; i < 8; ++i) {
        const int r = (g << 3) + i;
        const int code = ((r >> 4) << 8) + ((kt + 2) << 4) + (r & 15);
        pf[i] = *(const bf16x8*)(eb + ((size_t)code << 8) + c32);
      }
    }
    // compute: this wave's 16 codes (es rows cq*16 + r16) vs the block's 64 rows
    const unsigned short* esr = &esc[((cq << 4) + r16) * 264 + (quad << 3)];
    floatx4 acc0 = {0.f,0.f,0.f,0.f}, acc1 = {0.f,0.f,0.f,0.f};
    floatx4 acc2 = {0.f,0.f,0.f,0.f}, acc3 = {0.f,0.f,0.f,0.f};
    for (int ci = 0; ci < 8; ++ci) {
      const bf16x8 bfr = *(const bf16x8*)(esr + (ci << 5));  // 1 read feeds 4 MFMAs
      acc0 = __builtin_amdgcn_mfma_f32_16x16x32_bf16(a[0][ci], bfr, acc0, 0, 0, 0);
      acc1 = __builtin_amdgcn_mfma_f32_16x16x32_bf16(a[1][ci], bfr, acc1, 0, 0, 0);
      acc2 = __builtin_amdgcn_mfma_f32_16x16x32_bf16(a[2][ci], bfr, acc2, 0, 0, 0);
      acc3 = __builtin_amdgcn_mfma_f32_16x16x32_bf16(a[3][ci], bfr, acc3, 0, 0, 0);
    }
    const int kglob = (cq << 8) + (kt << 4) + r16;
    const float h = hn_l[kglob];
    for (int r = 0; r < 4; ++r) {              // D: row = quad*4 + r, col(code) = r16
      float v;
      v = acc0[r] - h; if (v > bv[0][r]) { bv[0][r] = v; bi[0][r] = kglob; }
      v = acc1[r] - h; if (v > bv[1][r]) { bv[1][r] = v; bi[1][r] = kglob; }
      v = acc2[r] - h; if (v > bv[2][r]) { bv[2][r] = v; bi[2][r] = kglob; }
      v = acc3[r] - h; if (v > bv[3][r]) { bv[3][r] = v; bi[3][r] = kglob; }
    }
    __syncthreads();                           // my reads + my writes done before buffers flip
    cur ^= 1;
  }

  // reduce across the 16 code-columns (within each 16-lane group); ties -> lowest index
  for (int off = 8; off >= 1; off >>= 1)
    for (int rg = 0; rg < 4; ++rg)
      for (int r = 0; r < 4; ++r) {
        const float ov = __shfl_xor(bv[rg][r], off, 64);
        const int   oi = __shfl_xor(bi[rg][r], off, 64);
        if (ov > bv[rg][r] || (ov == bv[rg][r] && oi < bi[rg][r])) { bv[rg][r] = ov; bi[rg][r] = oi; }
      }
  if (r16 == 0) {
    for (int rg = 0; rg < 4; ++rg)
      for (int r = 0; r < 4; ++r) {
        const int row = (rg << 4) + (quad << 2) + r;
        bvs[(cq << 6) + row] = bv[rg][r];
        bis[(cq << 6) + row] = bi[rg][r];
      }
  }
  __syncthreads();

  // merge the 4 code-quarters (ascending q: strict > keeps lowest code on ties) + loss
  if (t < 64) {
    float vm = bvs[t]; int im = bis[t];
    for (int q = 1; q < 4; ++q) {
      const float v = bvs[(q << 6) + t];
      if (v > vm) { vm = v; im = bis[(q << 6) + t]; }
    }
    idx_l[t] = im;
    float lv = xn2[n0 + t] - 2.f * vm;         // = ||x_n - e_{im}||^2
    for (int off = 32; off >= 1; off >>= 1) lv += __shfl_xor(lv, off, 64);
    if (t == 0) atomicAdd(loss, lv * (1.25f / 8388608.0f));
  }
  __syncthreads();                             // phase-A LDS (es) dead; sel may overwrite

  // gather winning code rows into LDS (coalesced 256B loads from L2-resident emb)
  for (int i = 0; i < 16; ++i) {
    const int row = (cq << 4) + i;
    const float* er = emb + ((size_t)idx_l[row] << 8);
    for (int j = 0; j < 4; ++j)
      sel[row * 257 + (j << 6) + lane] = er[(j << 6) + lane];
  }
  __syncthreads();
  // write out: float4 along hw (16B/lane), 256B segments per c
  const int hwq = t & 15, cg = t >> 4;
  const size_t base = ((size_t)b << 18);       // b*256*1024
  for (int it = 0; it < 16; ++it) {
    const int c = (it << 4) + cg;
    float4 v;
    v.x = sel[(hwq * 4 + 0) * 257 + c];
    v.y = sel[(hwq * 4 + 1) * 257 + c];
    v.z = sel[(hwq * 4 + 2) * 257 + c];
    v.w = sel[(hwq * 4 + 3) * 257 + c];
    *(float4*)(out + base + ((size_t)c << 10) + hw0 + (hwq << 2)) = v;
  }
}

extern "C" void kernel_launch(void* const* d_in, const int* in_sizes, int n_in,
                              void* d_out, int out_size, void* d_ws, size_t ws_size,
                              hipStream_t stream) {
  const float* x   = (const float*)d_in[0];
  const float* emb = (const float*)d_in[1];
  float* out  = (float*)d_out;
  float* loss = out + 8388608;

  char* ws = (char*)d_ws;
  unsigned short* xb = (unsigned short*)(ws);              // 16,777,216 B
  unsigned short* eb = (unsigned short*)(ws + 16777216);   //    524,288 B
  float* hn   = (float*)(ws + 17301504);                   //      4,096 B
  float* xn2  = (float*)(ws + 17305600);                   //    131,072 B

  k_prep<<<576, 256, 0, stream>>>(x, emb, xb, xn2, eb, hn, loss);
  k_fullk<<<512, 256, 0, stream>>>(xb, eb, hn, xn2, emb, out, loss);
}

// Round 5
// 122.453 us; speedup vs baseline: 1.1356x; 1.0235x over previous
//
#include <hip/hip_runtime.h>

#define NROW 32768
#define KCODE 1024

typedef short bf16x8 __attribute__((ext_vector_type(8)));
typedef float floatx4 __attribute__((ext_vector_type(4)));

// fp32 -> bf16 round-to-nearest-even (finite inputs)
static __device__ __forceinline__ unsigned short f2bf(float f) {
  unsigned int x = __float_as_uint(f);
  x += 0x7fffu + ((x >> 16) & 1u);
  return (unsigned short)(x >> 16);
}

// KA: blocks 0..511  : x [32][256][1024] f32 -> xb [N][C] bf16 (transpose) + xn2[n] = sum x^2 (fp32)
//     blocks 512..575: emb -> eb bf16 + hn[k] = 0.5*||e_k||^2 ; block 512 zeroes the loss slot
// (unchanged from the verified 135us version)
__global__ __launch_bounds__(256) void k_prep(const float* __restrict__ x,
                                              const float* __restrict__ emb,
                                              unsigned short* __restrict__ xb,
                                              float* __restrict__ xn2,
                                              unsigned short* __restrict__ eb,
                                              float* __restrict__ hn,
                                              float* __restrict__ loss) {
  __shared__ unsigned short tile[256 * 66];  // stride 66 shorts -> 33 dwords (odd): <=4-way banks
  __shared__ float xred[256];
  const int t = threadIdx.x;
  const int bid = blockIdx.x;
  if (bid < 512) {
    const int b = bid >> 4, ht = bid & 15;
    const int hw0 = ht << 6;
    const int n0 = (b << 10) + hw0;
    const int hw_l = t & 63, cs = t >> 6;
    float ss = 0.f;
    const float* xp = x + (((b << 8) + cs) << 10) + hw0 + hw_l;
    for (int i = 0; i < 64; ++i) {            // c = i*4 + cs, coalesced 256B segments along hw
      const int c = (i << 2) + cs;
      const float v = xp[(size_t)i << 12];
      ss += v * v;
      tile[c * 66 + hw_l] = f2bf(v);
    }
    xred[t] = ss;
    __syncthreads();
    if (t < 64) xn2[n0 + t] = xred[t] + xred[t + 64] + xred[t + 128] + xred[t + 192];
    // phase 2: write xb coalesced along c (4B = 2 bf16 per thread)
    const int c2 = (t & 127) * 2, hs = t >> 7;
    for (int i = 0; i < 32; ++i) {
      const int row = (i << 1) + hs;
      const unsigned int u0 = tile[c2 * 66 + row];
      const unsigned int u1 = tile[(c2 + 1) * 66 + row];
      *(unsigned int*)(xb + (((size_t)(n0 + row)) << 8) + c2) = u0 | (u1 << 16);
    }
  } else {
    if (bid == 512 && t == 0) *loss = 0.f;   // KB5 (later dispatch) is the only reader/adder
    const int w = t >> 6, lane = t & 63;
    const int kb = ((bid - 512) << 4) + (w << 2);
    for (int jj = 0; jj < 4; ++jj) {
      const int k = kb + jj;
      const float* er = emb + (k << 8);
      unsigned short* eo = eb + (k << 8);
      float ss = 0.f;
      for (int j = 0; j < 4; ++j) {
        const float v = er[j * 64 + lane];
        ss += v * v;
        eo[j * 64 + lane] = f2bf(v);
      }
      for (int off = 32; off >= 1; off >>= 1) ss += __shfl_xor(ss, off, 64);
      if (lane == 0) hn[k] = 0.5f * ss;
    }
  }
}

// KB5 (fused, BARRIER-FREE main loop): 512 blocks x 256 thr x 64 rows, FULL 1024 codes/block.
// R2/R4 post-mortem: per-tile __syncthreads at both 1 and 2 blocks/CU = ~44us, MfmaUtil 14%
// -- the compiler's vmcnt(0)+lgkmcnt(0) drain before every s_barrier serializes each tile
// against its own L2 prefetch (m97-structure mechanism); co-resident blocks run lockstep and
// don't mask it. KEY FACT: the staging layout is ALREADY wave-private -- wave w (g=2w,2w+1)
// writes exactly es rows 16w..16w+15, which are exactly the rows wave cq=w reads. So the
// main-loop barrier protects nothing. This version: hn_l fill made wave-private too, and ALL
// barriers removed from prologue+main loop. Per-wave in-order DS ops + compiler lgkmcnt give
// RAW safety on each wave's own double buffer; waves drift freely (L2 latency self-covered).
// Cross-wave barriers remain only at the tail (bvs/bis merge, sel overlay) -- 4 total.
// Numerics bit-identical to the verified R4 kernel (absmax 0.001930237).
__global__ __launch_bounds__(256, 2) void k_fullk(const unsigned short* __restrict__ xb,
                                                  const unsigned short* __restrict__ eb,
                                                  const float* __restrict__ hn,
                                                  const float* __restrict__ xn2,
                                                  const float* __restrict__ emb,
                                                  float* __restrict__ out,
                                                  float* __restrict__ loss) {
  // LDS map (bytes):
  //   [0, 67584)        es[2][64*264] shorts (double buffer; 33792 B each)
  //                     -- overlaid later by sel[64][257] f32 (65792 B)
  //   [67584, 71680)    hn_l[1024] f32
  //   [71680, 72704)    bvs[4][64] f32
  //   [72704, 73728)    bis[4][64] i32
  //   [73728, 73984)    idx_l[64] i32
  __shared__ __align__(16) char smem[73984];
  unsigned short* es0 = (unsigned short*)smem;
  unsigned short* es1 = (unsigned short*)(smem + 33792);
  float* sel  = (float*)smem;
  float* hn_l = (float*)(smem + 67584);
  float* bvs  = (float*)(smem + 71680);
  int*   bis  = (int*)(smem + 72704);
  int*   idx_l = (int*)(smem + 73728);

  const int t = threadIdx.x;
  const int cq = t >> 6, lane = t & 63;        // wave = code-quarter
  const int r16 = lane & 15, quad = lane >> 4;
  const int n0 = blockIdx.x << 6;              // 64 rows/block
  const int b = n0 >> 10, hw0 = n0 & 1023;

  // hn quarter, WAVE-PRIVATE (wave cq reads only hn_l[cq*256 .. cq*256+256))
  for (int i = 0; i < 4; ++i)
    hn_l[(cq << 8) + (i << 6) + lane] = hn[(cq << 8) + (i << 6) + lane];

  // A fragments: rows n0 + rg*16 + r16 (all 4 waves same rows; L1 dedups), k = quad*8 + ci*32
  bf16x8 a[4][8];
  for (int rg = 0; rg < 4; ++rg) {
    const unsigned short* xr = xb + (((size_t)(n0 + (rg << 4) + r16)) << 8) + (quad << 3);
    for (int ci = 0; ci < 8; ++ci) a[rg][ci] = *(const bf16x8*)(xr + (ci << 5));
  }

  // staging (wave-private): thread (g = t>>5, c32 = (t&31)*8 shorts) stages es rows g*8+i.
  // wave w covers g = 2w, 2w+1 -> rows 16w..16w+15 == exactly the rows wave cq=w reads.
  // es row r <-> code (r>>4)*256 + kt*16 + (r&15)
  const int g = t >> 5, c32 = (t & 31) << 3;
  bf16x8 pf[8];

  // prologue: tile0 -> es0; issue tile1 prefetch (no barrier: rows + hn_l are wave-private)
  {
    for (int i = 0; i < 8; ++i) {
      const int r = (g << 3) + i;
      const int code = ((r >> 4) << 8) + (r & 15);                  // kt=0
      pf[i] = *(const bf16x8*)(eb + ((size_t)code << 8) + c32);
    }
    for (int i = 0; i < 8; ++i) *(bf16x8*)(&es0[((g << 3) + i) * 264 + c32]) = pf[i];
    for (int i = 0; i < 8; ++i) {
      const int r = (g << 3) + i;
      const int code = ((r >> 4) << 8) + 16 + (r & 15);             // kt=1
      pf[i] = *(const bf16x8*)(eb + ((size_t)code << 8) + c32);
    }
  }

  float bv[4][4]; int bi[4][4];
  for (int rg = 0; rg < 4; ++rg)
    for (int r = 0; r < 4; ++r) { bv[rg][r] = -3.4e38f; bi[rg][r] = 0; }

  int cur = 0;
  for (int kt = 0; kt < 16; ++kt) {
    unsigned short* esc = cur ? es1 : es0;
    unsigned short* esn = cur ? es0 : es1;
    if (kt < 15)                               // write tile kt+1 (pf) into the other buffer
      for (int i = 0; i < 8; ++i) *(bf16x8*)(&esn[((g << 3) + i) * 264 + c32]) = pf[i];
    if (kt < 14) {                             // issue prefetch of tile kt+2
      for (int i = 0; i < 8; ++i) {
        const int r = (g << 3) + i;
        const int code = ((r >> 4) << 8) + ((kt + 2) << 4) + (r & 15);
        pf[i] = *(const bf16x8*)(eb + ((size_t)code << 8) + c32);
      }
    }
    // compute: this wave's 16 codes (es rows cq*16 + r16) vs the block's 64 rows
    const unsigned short* esr = &esc[((cq << 4) + r16) * 264 + (quad << 3)];
    floatx4 acc0 = {0.f,0.f,0.f,0.f}, acc1 = {0.f,0.f,0.f,0.f};
    floatx4 acc2 = {0.f,0.f,0.f,0.f}, acc3 = {0.f,0.f,0.f,0.f};
    for (int ci = 0; ci < 8; ++ci) {
      const bf16x8 bfr = *(const bf16x8*)(esr + (ci << 5));  // 1 read feeds 4 MFMAs
      acc0 = __builtin_amdgcn_mfma_f32_16x16x32_bf16(a[0][ci], bfr, acc0, 0, 0, 0);
      acc1 = __builtin_amdgcn_mfma_f32_16x16x32_bf16(a[1][ci], bfr, acc1, 0, 0, 0);
      acc2 = __builtin_amdgcn_mfma_f32_16x16x32_bf16(a[2][ci], bfr, acc2, 0, 0, 0);
      acc3 = __builtin_amdgcn_mfma_f32_16x16x32_bf16(a[3][ci], bfr, acc3, 0, 0, 0);
    }
    const int kglob = (cq << 8) + (kt << 4) + r16;
    const float h = hn_l[kglob];
    for (int r = 0; r < 4; ++r) {              // D: row = quad*4 + r, col(code) = r16
      float v;
      v = acc0[r] - h; if (v > bv[0][r]) { bv[0][r] = v; bi[0][r] = kglob; }
      v = acc1[r] - h; if (v > bv[1][r]) { bv[1][r] = v; bi[1][r] = kglob; }
      v = acc2[r] - h; if (v > bv[2][r]) { bv[2][r] = v; bi[2][r] = kglob; }
      v = acc3[r] - h; if (v > bv[3][r]) { bv[3][r] = v; bi[3][r] = kglob; }
    }
    cur ^= 1;                                  // wave-private flip; no barrier
  }

  // reduce across the 16 code-columns (within each 16-lane group); ties -> lowest index
  for (int off = 8; off >= 1; off >>= 1)
    for (int rg = 0; rg < 4; ++rg)
      for (int r = 0; r < 4; ++r) {
        const float ov = __shfl_xor(bv[rg][r], off, 64);
        const int   oi = __shfl_xor(bi[rg][r], off, 64);
        if (ov > bv[rg][r] || (ov == bv[rg][r] && oi < bi[rg][r])) { bv[rg][r] = ov; bi[rg][r] = oi; }
      }
  if (r16 == 0) {
    for (int rg = 0; rg < 4; ++rg)
      for (int r = 0; r < 4; ++r) {
        const int row = (rg << 4) + (quad << 2) + r;
        bvs[(cq << 6) + row] = bv[rg][r];
        bis[(cq << 6) + row] = bi[rg][r];
      }
  }
  __syncthreads();                             // all quarters' bvs/bis visible

  // merge the 4 code-quarters (ascending q: strict > keeps lowest code on ties) + loss
  if (t < 64) {
    float vm = bvs[t]; int im = bis[t];
    for (int q = 1; q < 4; ++q) {
      const float v = bvs[(q << 6) + t];
      if (v > vm) { vm = v; im = bis[(q << 6) + t]; }
    }
    idx_l[t] = im;
    float lv = xn2[n0 + t] - 2.f * vm;         // = ||x_n - e_{im}||^2
    for (int off = 32; off >= 1; off >>= 1) lv += __shfl_xor(lv, off, 64);
    if (t == 0) atomicAdd(loss, lv * (1.25f / 8388608.0f));
  }
  __syncthreads();                             // es dead + idx_l ready; sel may overwrite

  // gather winning code rows into LDS (coalesced 256B loads from L2-resident emb)
  for (int i = 0; i < 16; ++i) {
    const int row = (cq << 4) + i;
    const float* er = emb + ((size_t)idx_l[row] << 8);
    for (int j = 0; j < 4; ++j)
      sel[row * 257 + (j << 6) + lane] = er[(j << 6) + lane];
  }
  __syncthreads();
  // write out: float4 along hw (16B/lane), 256B segments per c
  const int hwq = t & 15, cg = t >> 4;
  const size_t base = ((size_t)b << 18);       // b*256*1024
  for (int it = 0; it < 16; ++it) {
    const int c = (it << 4) + cg;
    float4 v;
    v.x = sel[(hwq * 4 + 0) * 257 + c];
    v.y = sel[(hwq * 4 + 1) * 257 + c];
    v.z = sel[(hwq * 4 + 2) * 257 + c];
    v.w = sel[(hwq * 4 + 3) * 257 + c];
    *(float4*)(out + base + ((size_t)c << 10) + hw0 + (hwq << 2)) = v;
  }
}

extern "C" void kernel_launch(void* const* d_in, const int* in_sizes, int n_in,
                              void* d_out, int out_size, void* d_ws, size_t ws_size,
                              hipStream_t stream) {
  const float* x   = (const float*)d_in[0];
  const float* emb = (const float*)d_in[1];
  float* out  = (float*)d_out;
  float* loss = out + 8388608;

  char* ws = (char*)d_ws;
  unsigned short* xb = (unsigned short*)(ws);              // 16,777,216 B
  unsigned short* eb = (unsigned short*)(ws + 16777216);   //    524,288 B
  float* hn   = (float*)(ws + 17301504);                   //      4,096 B
  float* xn2  = (float*)(ws + 17305600);                   //    131,072 B

  k_prep<<<576, 256, 0, stream>>>(x, emb, xb, xn2, eb, hn, loss);
  k_fullk<<<512, 256, 0, stream>>>(xb, eb, hn, xn2, emb, out, loss);
}

// Round 6
// 114.308 us; speedup vs baseline: 1.2165x; 1.0713x over previous
//
#include <hip/hip_runtime.h>

typedef short bf16x8 __attribute__((ext_vector_type(8)));
typedef float floatx4 __attribute__((ext_vector_type(4)));

// fp32 -> bf16 round-to-nearest-even (finite inputs)
static __device__ __forceinline__ unsigned short f2bf(float f) {
  unsigned int x = __float_as_uint(f);
  x += 0x7fffu + ((x >> 16) & 1u);
  return (unsigned short)(x >> 16);
}

// KP (emb only, 64 blocks): emb -> eb bf16 + hn[k] = 0.5*||e_k||^2 ; block 0 zeroes loss.
// R5 post-mortem: the old 576-block k_prep measured ~37us (masked in top-5 by 43us poison
// fills) -- its x->xb transpose (31MB HBM round-trip) is now fused into k_fullk's prologue.
__global__ __launch_bounds__(256) void k_prep(const float* __restrict__ emb,
                                              unsigned short* __restrict__ eb,
                                              float* __restrict__ hn,
                                              float* __restrict__ loss) {
  const int t = threadIdx.x, bid = blockIdx.x;
  if (bid == 0 && t == 0) *loss = 0.f;       // k_fullk (later dispatch) is the only reader/adder
  const int w = t >> 6, lane = t & 63;
  const int kb = (bid << 4) + (w << 2);
  for (int jj = 0; jj < 4; ++jj) {
    const int k = kb + jj;
    const float* er = emb + (k << 8);
    unsigned short* eo = eb + (k << 8);
    float ss = 0.f;
    for (int j = 0; j < 4; ++j) {
      const float v = er[j * 64 + lane];
      ss += v * v;
      eo[j * 64 + lane] = f2bf(v);
    }
    for (int off = 32; off >= 1; off >>= 1) ss += __shfl_xor(ss, off, 64);
    if (lane == 0) hn[k] = 0.5f * ss;
  }
}

// KB6 (fully fused): 512 blocks x 256 thr x 64 rows, FULL 1024 codes/block.
//  - PROLOGUE (new): load x[b][all c][hw0..hw0+63] directly (64KB/block, coalesced 256B
//    segments -- same pattern as old k_prep), f2bf -> tile2[hw][c] (stride 264: 2 lanes/slot
//    per 16-lane phase on ds_write_b128), per-thread ss -> xn2_l in LDS (never leaves chip).
//    Each thread packs 8 consecutive c per row -> ONE ds_write_b128 (no b16 scatter).
//    Waves then read a[4][8] frags from tile2 -- bf16 values and MFMA order BIT-IDENTICAL
//    to the xb path, so argmax indices are unchanged.
//  - MAIN LOOP: unchanged from R5 (barrier-free, wave-private es double-buffer, prefetch
//    2 tiles ahead). tile2's LDS region is reused as es0 after a one-time barrier.
//  - TAIL: unchanged; loss uses xn2_l.
// xb and xn2 global buffers deleted: -31MB HBM, -1 large dispatch (~37us -> ~3us).
__global__ __launch_bounds__(256, 2) void k_fullk(const float* __restrict__ x,
                                                  const unsigned short* __restrict__ eb,
                                                  const float* __restrict__ hn,
                                                  const float* __restrict__ emb,
                                                  float* __restrict__ out,
                                                  float* __restrict__ loss) {
  // LDS map (bytes):
  //   [0, 33792)        tile2[64*264] shorts (x-transpose), then es0, then sel[0:...)
  //   [33792, 67584)    es1 ; sel[64][257] f32 overlays [0, 65792) at the tail
  //   [67584, 71680)    hn_l[1024] f32
  //   [71680, 72704)    bvs[4][64] f32  (prologue: xred[256] f32 overlay -- dead before bvs)
  //   [72704, 73728)    bis[4][64] i32
  //   [73728, 73984)    idx_l[64] i32
  //   [73984, 74240)    xn2_l[64] f32
  __shared__ __align__(16) char smem[74240];
  unsigned short* es0 = (unsigned short*)smem;           // == tile2
  unsigned short* es1 = (unsigned short*)(smem + 33792);
  float* sel   = (float*)smem;
  float* hn_l  = (float*)(smem + 67584);
  float* bvs   = (float*)(smem + 71680);
  float* xred  = (float*)(smem + 71680);                 // prologue-only overlay
  int*   bis   = (int*)(smem + 72704);
  int*   idx_l = (int*)(smem + 73728);
  float* xn2_l = (float*)(smem + 73984);

  const int t = threadIdx.x;
  const int cq = t >> 6, lane = t & 63;        // wave = code-quarter
  const int r16 = lane & 15, quad = lane >> 4;
  const int n0 = blockIdx.x << 6;              // 64 rows/block
  const int b = n0 >> 10, hw0 = n0 & 1023;

  // ---- phase 0: x -> tile2 (bf16) + per-thread ss ----
  {
    float ss = 0.f;
    const float* xp = x + (((size_t)b << 18)) + hw0 + lane;   // + c*1024 floats
    for (int i = 0; i < 8; ++i) {
      const int c8 = (i << 2) + cq;            // 8 c-groups of 8 per thread; wave-uniform c8
      bf16x8 pk;
      for (int j = 0; j < 8; ++j) {
        const float v = xp[(size_t)((c8 << 3) + j) << 10];
        ss += v * v;
        pk[j] = (short)f2bf(v);
      }
      *(bf16x8*)(&es0[lane * 264 + (c8 << 3)]) = pk;          // tile2[hw][c], 1x b128/group
    }
    xred[t] = ss;
  }
  __syncthreads();                             // tile2 + xred complete
  if (t < 64) xn2_l[t] = xred[t] + xred[t + 64] + xred[t + 128] + xred[t + 192];

  // A fragments from tile2: rows rg*16 + r16, c = quad*8 + ci*32 (bit-identical to xb path)
  bf16x8 a[4][8];
  for (int rg = 0; rg < 4; ++rg) {
    const unsigned short* tr = es0 + ((rg << 4) + r16) * 264 + (quad << 3);
    for (int ci = 0; ci < 8; ++ci) a[rg][ci] = *(const bf16x8*)(tr + (ci << 5));
  }
  __syncthreads();                             // tile2 consumed; es0 staging may overwrite

  // hn quarter, WAVE-PRIVATE (wave cq reads only hn_l[cq*256 .. +256))
  for (int i = 0; i < 4; ++i)
    hn_l[(cq << 8) + (i << 6) + lane] = hn[(cq << 8) + (i << 6) + lane];

  // staging (wave-private): thread (g = t>>5, c32 = (t&31)*8 shorts) stages es rows g*8+i.
  // wave w covers g = 2w, 2w+1 -> rows 16w..16w+15 == exactly the rows wave cq=w reads.
  // es row r <-> code (r>>4)*256 + kt*16 + (r&15)
  const int g = t >> 5, c32 = (t & 31) << 3;
  bf16x8 pf[8];

  // prologue: tile0 -> es0; issue tile1 prefetch (no barrier: rows + hn_l are wave-private)
  {
    for (int i = 0; i < 8; ++i) {
      const int r = (g << 3) + i;
      const int code = ((r >> 4) << 8) + (r & 15);                  // kt=0
      pf[i] = *(const bf16x8*)(eb + ((size_t)code << 8) + c32);
    }
    for (int i = 0; i < 8; ++i) *(bf16x8*)(&es0[((g << 3) + i) * 264 + c32]) = pf[i];
    for (int i = 0; i < 8; ++i) {
      const int r = (g << 3) + i;
      const int code = ((r >> 4) << 8) + 16 + (r & 15);             // kt=1
      pf[i] = *(const bf16x8*)(eb + ((size_t)code << 8) + c32);
    }
  }

  float bv[4][4]; int bi[4][4];
  for (int rg = 0; rg < 4; ++rg)
    for (int r = 0; r < 4; ++r) { bv[rg][r] = -3.4e38f; bi[rg][r] = 0; }

  int cur = 0;
  for (int kt = 0; kt < 16; ++kt) {
    unsigned short* esc = cur ? es1 : es0;
    unsigned short* esn = cur ? es0 : es1;
    if (kt < 15)                               // write tile kt+1 (pf) into the other buffer
      for (int i = 0; i < 8; ++i) *(bf16x8*)(&esn[((g << 3) + i) * 264 + c32]) = pf[i];
    if (kt < 14) {                             // issue prefetch of tile kt+2
      for (int i = 0; i < 8; ++i) {
        const int r = (g << 3) + i;
        const int code = ((r >> 4) << 8) + ((kt + 2) << 4) + (r & 15);
        pf[i] = *(const bf16x8*)(eb + ((size_t)code << 8) + c32);
      }
    }
    // compute: this wave's 16 codes (es rows cq*16 + r16) vs the block's 64 rows
    const unsigned short* esr = &esc[((cq << 4) + r16) * 264 + (quad << 3)];
    floatx4 acc0 = {0.f,0.f,0.f,0.f}, acc1 = {0.f,0.f,0.f,0.f};
    floatx4 acc2 = {0.f,0.f,0.f,0.f}, acc3 = {0.f,0.f,0.f,0.f};
    for (int ci = 0; ci < 8; ++ci) {
      const bf16x8 bfr = *(const bf16x8*)(esr + (ci << 5));  // 1 read feeds 4 MFMAs
      acc0 = __builtin_amdgcn_mfma_f32_16x16x32_bf16(a[0][ci], bfr, acc0, 0, 0, 0);
      acc1 = __builtin_amdgcn_mfma_f32_16x16x32_bf16(a[1][ci], bfr, acc1, 0, 0, 0);
      acc2 = __builtin_amdgcn_mfma_f32_16x16x32_bf16(a[2][ci], bfr, acc2, 0, 0, 0);
      acc3 = __builtin_amdgcn_mfma_f32_16x16x32_bf16(a[3][ci], bfr, acc3, 0, 0, 0);
    }
    const int kglob = (cq << 8) + (kt << 4) + r16;
    const float h = hn_l[kglob];
    for (int r = 0; r < 4; ++r) {              // D: row = quad*4 + r, col(code) = r16
      float v;
      v = acc0[r] - h; if (v > bv[0][r]) { bv[0][r] = v; bi[0][r] = kglob; }
      v = acc1[r] - h; if (v > bv[1][r]) { bv[1][r] = v; bi[1][r] = kglob; }
      v = acc2[r] - h; if (v > bv[2][r]) { bv[2][r] = v; bi[2][r] = kglob; }
      v = acc3[r] - h; if (v > bv[3][r]) { bv[3][r] = v; bi[3][r] = kglob; }
    }
    cur ^= 1;                                  // wave-private flip; no barrier
  }

  // reduce across the 16 code-columns (within each 16-lane group); ties -> lowest index
  for (int off = 8; off >= 1; off >>= 1)
    for (int rg = 0; rg < 4; ++rg)
      for (int r = 0; r < 4; ++r) {
        const float ov = __shfl_xor(bv[rg][r], off, 64);
        const int   oi = __shfl_xor(bi[rg][r], off, 64);
        if (ov > bv[rg][r] || (ov == bv[rg][r] && oi < bi[rg][r])) { bv[rg][r] = ov; bi[rg][r] = oi; }
      }
  if (r16 == 0) {
    for (int rg = 0; rg < 4; ++rg)
      for (int r = 0; r < 4; ++r) {
        const int row = (rg << 4) + (quad << 2) + r;
        bvs[(cq << 6) + row] = bv[rg][r];
        bis[(cq << 6) + row] = bi[rg][r];
      }
  }
  __syncthreads();                             // all quarters' bvs/bis visible

  // merge the 4 code-quarters (ascending q: strict > keeps lowest code on ties) + loss
  if (t < 64) {
    float vm = bvs[t]; int im = bis[t];
    for (int q = 1; q < 4; ++q) {
      const float v = bvs[(q << 6) + t];
      if (v > vm) { vm = v; im = bis[(q << 6) + t]; }
    }
    idx_l[t] = im;
    float lv = xn2_l[t] - 2.f * vm;            // = ||x_n - e_{im}||^2
    for (int off = 32; off >= 1; off >>= 1) lv += __shfl_xor(lv, off, 64);
    if (t == 0) atomicAdd(loss, lv * (1.25f / 8388608.0f));
  }
  __syncthreads();                             // es dead + idx_l ready; sel may overwrite

  // gather winning code rows into LDS (coalesced 256B loads from L2-resident emb)
  for (int i = 0; i < 16; ++i) {
    const int row = (cq << 4) + i;
    const float* er = emb + ((size_t)idx_l[row] << 8);
    for (int j = 0; j < 4; ++j)
      sel[row * 257 + (j << 6) + lane] = er[(j << 6) + lane];
  }
  __syncthreads();
  // write out: float4 along hw (16B/lane), 256B segments per c
  const int hwq = t & 15, cg = t >> 4;
  const size_t base = ((size_t)b << 18);       // b*256*1024
  for (int it = 0; it < 16; ++it) {
    const int c = (it << 4) + cg;
    float4 v;
    v.x = sel[(hwq * 4 + 0) * 257 + c];
    v.y = sel[(hwq * 4 + 1) * 257 + c];
    v.z = sel[(hwq * 4 + 2) * 257 + c];
    v.w = sel[(hwq * 4 + 3) * 257 + c];
    *(float4*)(out + base + ((size_t)c << 10) + hw0 + (hwq << 2)) = v;
  }
}

extern "C" void kernel_launch(void* const* d_in, const int* in_sizes, int n_in,
                              void* d_out, int out_size, void* d_ws, size_t ws_size,
                              hipStream_t stream) {
  const float* x   = (const float*)d_in[0];
  const float* emb = (const float*)d_in[1];
  float* out  = (float*)d_out;
  float* loss = out + 8388608;

  char* ws = (char*)d_ws;
  unsigned short* eb = (unsigned short*)(ws);              // 524,288 B
  float* hn = (float*)(ws + 524288);                       //   4,096 B

  k_prep<<<64, 256, 0, stream>>>(emb, eb, hn, loss);
  k_fullk<<<512, 256, 0, stream>>>(x, eb, hn, emb, out, loss);
}

// Round 8
// 112.161 us; speedup vs baseline: 1.2398x; 1.0191x over previous
//
#include <hip/hip_runtime.h>

typedef short bf16x8 __attribute__((ext_vector_type(8)));
typedef short bf16x4 __attribute__((ext_vector_type(4)));
typedef float floatx4 __attribute__((ext_vector_type(4)));

// fp32 -> bf16 round-to-nearest-even (finite inputs)
static __device__ __forceinline__ unsigned short f2bf(float f) {
  unsigned int x = __float_as_uint(f);
  x += 0x7fffu + ((x >> 16) & 1u);
  return (unsigned short)(x >> 16);
}

// KP (emb only, 64 blocks): emb -> eb bf16 + hn[k] = 0.5*||e_k||^2 ; block 0 zeroes loss.
__global__ __launch_bounds__(256) void k_prep(const float* __restrict__ emb,
                                              unsigned short* __restrict__ eb,
                                              float* __restrict__ hn,
                                              float* __restrict__ loss) {
  const int t = threadIdx.x, bid = blockIdx.x;
  if (bid == 0 && t == 0) *loss = 0.f;       // k_fullk (later dispatch) is the only reader/adder
  const int w = t >> 6, lane = t & 63;
  const int kb = (bid << 4) + (w << 2);
  for (int jj = 0; jj < 4; ++jj) {
    const int k = kb + jj;
    const float* er = emb + (k << 8);
    unsigned short* eo = eb + (k << 8);
    float ss = 0.f;
    for (int j = 0; j < 4; ++j) {
      const float v = er[j * 64 + lane];
      ss += v * v;
      eo[j * 64 + lane] = f2bf(v);
    }
    for (int off = 32; off >= 1; off >>= 1) ss += __shfl_xor(ss, off, 64);
    if (lane == 0) hn[k] = 0.5f * ss;
  }
}

// KB7: 512 blocks x 256 thr x 64 rows, FULL 1024 codes/block, fused output.
// R6 post-mortem: phase-0 (x->LDS transpose via 64 scalar dword loads/thread with per-iter
// consumption) cost ~21us -- effective ~1.4 TB/s, the SAME rate the old 37us k_prep got with
// the same pattern. MLP starvation: ~1 outstanding 256B load per wave -> 0.7 GB/s/wave.
// FIX: float4 loads along hw (1KB/wave-instr => >=5.6 TB/s floor even if serialized), with a
// two-stage LDS transpose:
//   stage A: x float4 -> bf16x4 b64 writes into tmp[c][hw] (tmp overlays es1, dead til kt=0)
//   stage B: tmp b16 reads (2 lanes/dword: conflict-free) -> pack bf16x8 -> tile2[hw][c] b128
// A-frag bf16 values + E path + MFMA order BIT-IDENTICAL to R6 => indices unchanged; only
// xn2's fp32 sum order changes (loss epsilon). E-tile0 (pf0) global loads issued BEFORE
// stage A so L2 latency hides under the x read. Main loop unchanged (R5 barrier-free form).
// (R7 was an infra failure -- container died twice; identical resubmission, audit clean.)
__global__ __launch_bounds__(256, 2) void k_fullk(const float* __restrict__ x,
                                                  const unsigned short* __restrict__ eb,
                                                  const float* __restrict__ hn,
                                                  const float* __restrict__ emb,
                                                  float* __restrict__ out,
                                                  float* __restrict__ loss) {
  // LDS map (bytes):
  //   [0, 33792)        tile2[64*264] shorts == es0 (E dbuf 0); sel f32 overlays at tail
  //   [33792, 67584)    tmp[256*64] shorts (32768 B) == es1 (E dbuf 1)
  //   [67584, 71680)    xred2[4][256] f32 (prologue) == hn_l[1024] f32 (main loop)
  //   [71680, 72704)    bvs[4][64] f32
  //   [72704, 73728)    bis[4][64] i32
  //   [73728, 73984)    idx_l[64] i32
  //   [73984, 74240)    xn2_l[64] f32
  __shared__ __align__(16) char smem[74240];
  unsigned short* es0 = (unsigned short*)smem;
  unsigned short* es1 = (unsigned short*)(smem + 33792);
  unsigned short* tile2 = es0;
  unsigned short* tmp   = es1;
  float* sel   = (float*)smem;
  float* hn_l  = (float*)(smem + 67584);
  float* xred2 = (float*)(smem + 67584);
  float* bvs   = (float*)(smem + 71680);
  int*   bis   = (int*)(smem + 72704);
  int*   idx_l = (int*)(smem + 73728);
  float* xn2_l = (float*)(smem + 73984);

  const int t = threadIdx.x;
  const int cq = t >> 6, lane = t & 63;        // wave = code-quarter
  const int r16 = lane & 15, quad = lane >> 4;
  const int n0 = blockIdx.x << 6;              // 64 rows/block
  const int b = n0 >> 10, hw0 = n0 & 1023;

  // staging geometry (wave-private: wave w stages es rows 16w..16w+15 == rows wave cq=w reads)
  const int g = t >> 5, c32 = (t & 31) << 3;

  // ---- step 1: issue E-tile0 loads EARLY (latency hides under the x read) ----
  bf16x8 pf0[8];
  for (int i = 0; i < 8; ++i) {
    const int r = (g << 3) + i;
    const int code = ((r >> 4) << 8) + (r & 15);                    // kt=0
    pf0[i] = *(const bf16x8*)(eb + ((size_t)code << 8) + c32);
  }

  // ---- stage A: x float4 loads -> tmp[c][hw] (bf16), per-thread row-split ss ----
  {
    const int hwq = t & 15, cidx = t >> 4;
    const float* xpb = x + ((size_t)b << 18) + hw0 + (hwq << 2);
    float ss0 = 0.f, ss1 = 0.f, ss2 = 0.f, ss3 = 0.f;
    for (int p = 0; p < 16; ++p) {
      const int c = (p << 4) + cidx;
      const float4 v = *(const float4*)(xpb + ((size_t)c << 10));
      ss0 += v.x * v.x; ss1 += v.y * v.y; ss2 += v.z * v.z; ss3 += v.w * v.w;
      bf16x4 u;
      u[0] = (short)f2bf(v.x); u[1] = (short)f2bf(v.y);
      u[2] = (short)f2bf(v.z); u[3] = (short)f2bf(v.w);
      *(bf16x4*)(&tmp[(c << 6) + (hwq << 2)]) = u;                  // tmp[c*64 + hw]
    }
    xred2[t] = ss0; xred2[256 + t] = ss1; xred2[512 + t] = ss2; xred2[768 + t] = ss3;
  }
  __syncthreads();                             // tmp + xred2 complete

  // ---- stage B: tmp[c][hw] -> tile2[hw][c] (b16 reads are 2-lanes/dword: conflict-free) ----
  {
    const int row = t & 63, wv = t >> 6;
    for (int s = 0; s < 8; ++s) {
      const int c8 = wv + (s << 2);
      bf16x8 u;
      for (int k = 0; k < 8; ++k) u[k] = (short)tmp[(((c8 << 3) + k) << 6) + row];
      *(bf16x8*)(&tile2[row * 264 + (c8 << 3)]) = u;
    }
  }
  // xn2 reduce (wave 0; xred2 still live -- hn_l overwrite happens after barrier below)
  if (t < 64) {
    float s = 0.f;
    for (int ci2 = 0; ci2 < 16; ++ci2)
      s += xred2[(t & 3) * 256 + (ci2 << 4) + (t >> 2)];
    xn2_l[t] = s;
  }
  __syncthreads();                             // tile2 complete; xred2 consumed

  // A fragments from tile2: rows rg*16 + r16, c = quad*8 + ci*32 (bit-identical to R6)
  bf16x8 a[4][8];
  for (int rg = 0; rg < 4; ++rg) {
    const unsigned short* tr = tile2 + ((rg << 4) + r16) * 264 + (quad << 3);
    for (int ci = 0; ci < 8; ++ci) a[rg][ci] = *(const bf16x8*)(tr + (ci << 5));
  }
  // hn quarter, WAVE-PRIVATE (overlays xred2 -- dead now)
  for (int i = 0; i < 4; ++i)
    hn_l[(cq << 8) + (i << 6) + lane] = hn[(cq << 8) + (i << 6) + lane];
  __syncthreads();                             // tile2 consumed by all; es0 free

  // ---- E prologue: write preloaded tile0 -> es0; issue tile1 prefetch ----
  bf16x8 pf[8];
  for (int i = 0; i < 8; ++i) *(bf16x8*)(&es0[((g << 3) + i) * 264 + c32]) = pf0[i];
  for (int i = 0; i < 8; ++i) {
    const int r = (g << 3) + i;
    const int code = ((r >> 4) << 8) + 16 + (r & 15);               // kt=1
    pf[i] = *(const bf16x8*)(eb + ((size_t)code << 8) + c32);
  }

  float bv[4][4]; int bi[4][4];
  for (int rg = 0; rg < 4; ++rg)
    for (int r = 0; r < 4; ++r) { bv[rg][r] = -3.4e38f; bi[rg][r] = 0; }

  // ---- main loop: barrier-free, wave-private es double-buffer (unchanged from R5/R6) ----
  int cur = 0;
  for (int kt = 0; kt < 16; ++kt) {
    unsigned short* esc = cur ? es1 : es0;
    unsigned short* esn = cur ? es0 : es1;
    if (kt < 15)                               // write tile kt+1 (pf) into the other buffer
      for (int i = 0; i < 8; ++i) *(bf16x8*)(&esn[((g << 3) + i) * 264 + c32]) = pf[i];
    if (kt < 14) {                             // issue prefetch of tile kt+2
      for (int i = 0; i < 8; ++i) {
        const int r = (g << 3) + i;
        const int code = ((r >> 4) << 8) + ((kt + 2) << 4) + (r & 15);
        pf[i] = *(const bf16x8*)(eb + ((size_t)code << 8) + c32);
      }
    }
    // compute: this wave's 16 codes (es rows cq*16 + r16) vs the block's 64 rows
    const unsigned short* esr = &esc[((cq << 4) + r16) * 264 + (quad << 3)];
    floatx4 acc0 = {0.f,0.f,0.f,0.f}, acc1 = {0.f,0.f,0.f,0.f};
    floatx4 acc2 = {0.f,0.f,0.f,0.f}, acc3 = {0.f,0.f,0.f,0.f};
    for (int ci = 0; ci < 8; ++ci) {
      const bf16x8 bfr = *(const bf16x8*)(esr + (ci << 5));  // 1 read feeds 4 MFMAs
      acc0 = __builtin_amdgcn_mfma_f32_16x16x32_bf16(a[0][ci], bfr, acc0, 0, 0, 0);
      acc1 = __builtin_amdgcn_mfma_f32_16x16x32_bf16(a[1][ci], bfr, acc1, 0, 0, 0);
      acc2 = __builtin_amdgcn_mfma_f32_16x16x32_bf16(a[2][ci], bfr, acc2, 0, 0, 0);
      acc3 = __builtin_amdgcn_mfma_f32_16x16x32_bf16(a[3][ci], bfr, acc3, 0, 0, 0);
    }
    const int kglob = (cq << 8) + (kt << 4) + r16;
    const float h = hn_l[kglob];
    for (int r = 0; r < 4; ++r) {              // D: row = quad*4 + r, col(code) = r16
      float v;
      v = acc0[r] - h; if (v > bv[0][r]) { bv[0][r] = v; bi[0][r] = kglob; }
      v = acc1[r] - h; if (v > bv[1][r]) { bv[1][r] = v; bi[1][r] = kglob; }
      v = acc2[r] - h; if (v > bv[2][r]) { bv[2][r] = v; bi[2][r] = kglob; }
      v = acc3[r] - h; if (v > bv[3][r]) { bv[3][r] = v; bi[3][r] = kglob; }
    }
    cur ^= 1;                                  // wave-private flip; no barrier
  }

  // reduce across the 16 code-columns (within each 16-lane group); ties -> lowest index
  for (int off = 8; off >= 1; off >>= 1)
    for (int rg = 0; rg < 4; ++rg)
      for (int r = 0; r < 4; ++r) {
        const float ov = __shfl_xor(bv[rg][r], off, 64);
        const int   oi = __shfl_xor(bi[rg][r], off, 64);
        if (ov > bv[rg][r] || (ov == bv[rg][r] && oi < bi[rg][r])) { bv[rg][r] = ov; bi[rg][r] = oi; }
      }
  if (r16 == 0) {
    for (int rg = 0; rg < 4; ++rg)
      for (int r = 0; r < 4; ++r) {
        const int row = (rg << 4) + (quad << 2) + r;
        bvs[(cq << 6) + row] = bv[rg][r];
        bis[(cq << 6) + row] = bi[rg][r];
      }
  }
  __syncthreads();                             // all quarters' bvs/bis visible

  // merge the 4 code-quarters (ascending q: strict > keeps lowest code on ties) + loss
  if (t < 64) {
    float vm = bvs[t]; int im = bis[t];
    for (int q = 1; q < 4; ++q) {
      const float v = bvs[(q << 6) + t];
      if (v > vm) { vm = v; im = bis[(q << 6) + t]; }
    }
    idx_l[t] = im;
    float lv = xn2_l[t] - 2.f * vm;            // = ||x_n - e_{im}||^2
    for (int off = 32; off >= 1; off >>= 1) lv += __shfl_xor(lv, off, 64);
    if (t == 0) atomicAdd(loss, lv * (1.25f / 8388608.0f));
  }
  __syncthreads();                             // es dead + idx_l ready; sel may overwrite

  // gather winning code rows into LDS (coalesced 256B loads from L2-resident emb)
  for (int i = 0; i < 16; ++i) {
    const int row = (cq << 4) + i;
    const float* er = emb + ((size_t)idx_l[row] << 8);
    for (int j = 0; j < 4; ++j)
      sel[row * 257 + (j << 6) + lane] = er[(j << 6) + lane];
  }
  __syncthreads();
  // write out: float4 along hw (16B/lane), 256B segments per c
  const int hwq = t & 15, cg = t >> 4;
  const size_t base = ((size_t)b << 18);       // b*256*1024
  for (int it = 0; it < 16; ++it) {
    const int c = (it << 4) + cg;
    float4 v;
    v.x = sel[(hwq * 4 + 0) * 257 + c];
    v.y = sel[(hwq * 4 + 1) * 257 + c];
    v.z = sel[(hwq * 4 + 2) * 257 + c];
    v.w = sel[(hwq * 4 + 3) * 257 + c];
    *(float4*)(out + base + ((size_t)c << 10) + hw0 + (hwq << 2)) = v;
  }
}

extern "C" void kernel_launch(void* const* d_in, const int* in_sizes, int n_in,
                              void* d_out, int out_size, void* d_ws, size_t ws_size,
                              hipStream_t stream) {
  const float* x   = (const float*)d_in[0];
  const float* emb = (const float*)d_in[1];
  float* out  = (float*)d_out;
  float* loss = out + 8388608;

  char* ws = (char*)d_ws;
  unsigned short* eb = (unsigned short*)(ws);              // 524,288 B
  float* hn = (float*)(ws + 524288);                       //   4,096 B

  k_prep<<<64, 256, 0, stream>>>(emb, eb, hn, loss);
  k_fullk<<<512, 256, 0, stream>>>(x, eb, hn, emb, out, loss);
}